// Round 7
// baseline (426.138 us; speedup 1.0000x reference)
//
#include <hip/hip_runtime.h>

#define IN_DIM   256
#define OUT_DIM  64
#define NEG_SLOPE 0.01f
#define KPAD (IN_DIM + 8)     // bf16; +16B pad -> conflict-light ds accesses
#define MAXBUCK 2048
#define CAP     1024          // slots/bucket (mean 512, 22 sigma < 1024)
#define EPB     4096          // edges per multisplit block
#define ASTRIDE 65            // accum row stride (pad: rotates bank sets per dst)

typedef __attribute__((ext_vector_type(8))) short short8;   // 8 bf16
typedef __attribute__((ext_vector_type(4))) float f32x4;
typedef unsigned short ushort_t;

__device__ inline unsigned f2bf_u(float f) {
    unsigned u = __float_as_uint(f);
    return (u + 0x7FFF + ((u >> 16) & 1)) >> 16;            // RNE, low 16 bits
}
__device__ inline short f2bf(float f) { return (short)f2bf_u(f); }
__device__ inline float bf2f(unsigned u16) { return __uint_as_float(u16 << 16); }

// ---------------------------------------------------------------------------
// P0 (8 blocks): W (256x64 fp32 [k][n]) -> Wt (64x256 bf16 [n][k]).
// (cnt zeroing moved to hipMemsetAsync on the stream.)
// ---------------------------------------------------------------------------
__global__ __launch_bounds__(256)
void prep_kernel(const float* __restrict__ W, short* __restrict__ Wt)
{
    const int g = blockIdx.x * 256 + threadIdx.x;
    for (int i = g; i < IN_DIM * OUT_DIM; i += 8 * 256) {
        const int k = i & (IN_DIM - 1);
        const int n = i >> 8;                      // IN_DIM == 256
        Wt[i] = f2bf(W[(size_t)k * OUT_DIM + n]);
    }
}

// ---------------------------------------------------------------------------
// K1 (fused): blocks [0, ms_blocks) do the bucketed multisplit; the rest do
// the MFMA gemm (z = h@W + fused s_l/s_r). Data-independent halves overlap.
// ---------------------------------------------------------------------------
__global__ __launch_bounds__(256, 4)
void fused_kernel(const float* __restrict__ h, const short* __restrict__ Wt,
                  const float* __restrict__ a_attn,
                  ushort_t* __restrict__ z_bf, float* __restrict__ s_l,
                  float* __restrict__ s_r,
                  const int* __restrict__ esrc, const int* __restrict__ edst,
                  int* __restrict__ cnt, unsigned* __restrict__ perm,
                  int n_nodes, int n_edges, int nbuck, int ms_blocks)
{
    __shared__ union {
        short As[64 * KPAD];                                // 33792 B (gemm)
        struct { int hist[MAXBUCK]; int cur[MAXBUCK]; } m;  // 16384 B (multisplit)
    } sm;

    const int tid = threadIdx.x;

    if ((int)blockIdx.x < ms_blocks) {
        // ---------------- multisplit ----------------
        for (int i = tid; i < nbuck; i += 256) sm.m.hist[i] = 0;
        __syncthreads();
        const int base = blockIdx.x * EPB;
        unsigned pw[EPB / 256];
#pragma unroll
        for (int j = 0; j < EPB / 256; ++j) {
            const int i = base + j * 256 + tid;
            unsigned w = 0xFFFFFFFFu;
            if (i < n_edges) {
                const int d = edst[i];
                w = ((unsigned)d << 16) | (unsigned)esrc[i];
                atomicAdd(&sm.m.hist[d >> 5], 1);
            }
            pw[j] = w;
        }
        __syncthreads();
        for (int i = tid; i < nbuck; i += 256) {
            const int hv = sm.m.hist[i];
            if (hv) sm.m.cur[i] = i * CAP + atomicAdd(&cnt[i], hv);
        }
        __syncthreads();
#pragma unroll
        for (int j = 0; j < EPB / 256; ++j) {
            const unsigned w = pw[j];
            if (w != 0xFFFFFFFFu) {
                const int bk = (int)(w >> 21);
                const int pos = atomicAdd(&sm.m.cur[bk], 1);
                if (pos < (bk + 1) * CAP) perm[pos] = w;   // overflow guard
            }
        }
        return;
    }

    // ---------------- gemm: z = h @ W, fused s_l/s_r ----------------
    const int wave = tid >> 6;
    const int lane = tid & 63;
    const int nbase = ((int)blockIdx.x - ms_blocks) * 64;

    for (int i = tid; i < 64 * (IN_DIM / 4); i += 256) {
        const int m  = i >> 6;
        const int k4 = i & 63;
        int node = nbase + m;
        if (node >= n_nodes) node = n_nodes - 1;
        const float4 h4 = *(const float4*)&h[(size_t)node * IN_DIM + k4 * 4];
        uint2 p;
        p.x = f2bf_u(h4.x) | (f2bf_u(h4.y) << 16);
        p.y = f2bf_u(h4.z) | (f2bf_u(h4.w) << 16);
        *(uint2*)&sm.As[m * KPAD + k4 * 4] = p;
    }
    __syncthreads();

    f32x4 acc[4];
#pragma unroll
    for (int t = 0; t < 4; ++t) acc[t] = (f32x4){0.f, 0.f, 0.f, 0.f};

    const int col0 = lane & 15;
    const int quad = lane >> 4;
    const int mrow = wave * 16 + col0;
    const int kq   = quad * 8;

#pragma unroll
    for (int ks = 0; ks < IN_DIM / 32; ++ks) {
        const int kb = ks * 32 + kq;
        const short8 a = *(const short8*)&sm.As[mrow * KPAD + kb];
#pragma unroll
        for (int t = 0; t < 4; ++t) {
            const short8 b = *(const short8*)&Wt[(t * 16 + col0) * IN_DIM + kb];
            acc[t] = __builtin_amdgcn_mfma_f32_16x16x32_bf16(a, b, acc[t], 0, 0, 0);
        }
    }

    float al[4], ar[4];
#pragma unroll
    for (int t = 0; t < 4; ++t) {
        al[t] = a_attn[t * 16 + col0];
        ar[t] = a_attn[OUT_DIM + t * 16 + col0];
    }
#pragma unroll
    for (int r = 0; r < 4; ++r) {
        const int m = nbase + wave * 16 + quad * 4 + r;
        const bool live = m < n_nodes;
        float sl = 0.f, sr = 0.f;
#pragma unroll
        for (int t = 0; t < 4; ++t) {
            const float v = acc[t][r];
            if (live) z_bf[(size_t)m * OUT_DIM + t * 16 + col0] = (ushort_t)f2bf(v);
            sl += v * al[t];
            sr += v * ar[t];
        }
#pragma unroll
        for (int off = 1; off < 16; off <<= 1) {
            sl += __shfl_xor(sl, off, 16);
            sr += __shfl_xor(sr, off, 16);
        }
        if (live && col0 == 0) { s_l[m] = sl; s_r[m] = sr; }
    }
}

// ---------------------------------------------------------------------------
// K2: per-bucket softmax gather via LDS float-atomic accumulation.
// One 256-thr block per bucket (32 dsts). No CSR build: each quarter-wave
// (16 lanes) takes one edge per iteration (uniform work, no degree
// imbalance); lane c owns cols 4c..4c+3 and ds_add_f32's into the 32x65
// padded accumulator tile. Epilogue scales by 1/den, float4 stores.
// ---------------------------------------------------------------------------
__global__ __launch_bounds__(256)
void gather_kernel(const unsigned* __restrict__ perm, const int* __restrict__ cnt,
                   const float* __restrict__ s_l, const float* __restrict__ s_r,
                   const ushort_t* __restrict__ z_bf, float* __restrict__ out,
                   int n_nodes)
{
    __shared__ unsigned eds[CAP];            // 4096 B
    __shared__ float accum[32 * ASTRIDE];    // 8320 B
    __shared__ float denS[32];
    __shared__ float srS[32];

    const int tid = threadIdx.x;
    const int b   = blockIdx.x;
    int nE = cnt[b];
    if (nE > CAP) nE = CAP;

    for (int i = tid; i < 32 * ASTRIDE; i += 256) accum[i] = 0.f;
    if (tid < 32) {
        denS[tid] = 0.f;
        const int d = b * 32 + tid;
        srS[tid] = (d < n_nodes) ? s_r[d] : 0.f;
    }
    for (int i = tid; i < nE; i += 256) eds[i] = perm[(size_t)b * CAP + i];
    __syncthreads();

    const int qw = tid >> 4;      // quarter-wave id, 0..15
    const int c  = tid & 15;      // column quad

    for (int i = qw; i < nE; i += 32) {
        const int j = i + 16;
        const bool v1 = j < nE;
        const unsigned p0 = eds[i];
        const unsigned p1 = v1 ? eds[j] : p0;
        const int s0 = p0 & 0xFFFFu, ld0 = (p0 >> 16) & 31;
        const int s1 = p1 & 0xFFFFu, ld1 = (p1 >> 16) & 31;
        const float l0 = s_l[s0];
        const float l1 = s_l[s1];
        const uint2 q0 = *(const uint2*)&z_bf[(size_t)s0 * OUT_DIM + c * 4];
        const uint2 q1 = *(const uint2*)&z_bf[(size_t)s1 * OUT_DIM + c * 4];
        float e0 = l0 + srS[ld0];
        float e1 = l1 + srS[ld1];
        e0 = e0 > 0.f ? e0 : NEG_SLOPE * e0;
        e1 = e1 > 0.f ? e1 : NEG_SLOPE * e1;
        const float x0 = __expf(e0);
        const float x1 = __expf(e1);
        float* r0 = &accum[ld0 * ASTRIDE + c * 4];
        atomicAdd(&r0[0], x0 * bf2f(q0.x & 0xFFFFu));
        atomicAdd(&r0[1], x0 * bf2f(q0.x >> 16));
        atomicAdd(&r0[2], x0 * bf2f(q0.y & 0xFFFFu));
        atomicAdd(&r0[3], x0 * bf2f(q0.y >> 16));
        if (c == 0) atomicAdd(&denS[ld0], x0);
        if (v1) {
            float* r1 = &accum[ld1 * ASTRIDE + c * 4];
            atomicAdd(&r1[0], x1 * bf2f(q1.x & 0xFFFFu));
            atomicAdd(&r1[1], x1 * bf2f(q1.x >> 16));
            atomicAdd(&r1[2], x1 * bf2f(q1.y & 0xFFFFu));
            atomicAdd(&r1[3], x1 * bf2f(q1.y >> 16));
            if (c == 0) atomicAdd(&denS[ld1], x1);
        }
    }
    __syncthreads();

    // epilogue: 32 dsts x 16 col-quads = 512 float4 stores over 256 threads
    for (int i = tid; i < 32 * 16; i += 256) {
        const int ld = i >> 4;
        const int cq = i & 15;
        const int d  = b * 32 + ld;
        if (d < n_nodes) {
            const float dn = denS[ld];
            const float inv = dn > 0.f ? 1.f / dn : 0.f;
            const float* r = &accum[ld * ASTRIDE + cq * 4];
            float4 o;
            o.x = r[0] * inv; o.y = r[1] * inv; o.z = r[2] * inv; o.w = r[3] * inv;
            *(float4*)&out[(size_t)d * OUT_DIM + cq * 4] = o;
        }
    }
}

extern "C" void kernel_launch(void* const* d_in, const int* in_sizes, int n_in,
                              void* d_out, int out_size, void* d_ws, size_t ws_size,
                              hipStream_t stream)
{
    const float* h        = (const float*)d_in[0];
    const int*   edge_src = (const int*)  d_in[1];
    const int*   edge_dst = (const int*)  d_in[2];
    const float* W        = (const float*)d_in[3];
    const float* a_attn   = (const float*)d_in[4];
    float*       out      = (float*)d_out;

    const int n_nodes = in_sizes[0] / IN_DIM;   // 50000
    const int n_edges = in_sizes[1];            // 800000
    const int nbuck   = (n_nodes + 31) >> 5;    // 1563

    // ---- workspace layout (16B-aligned regions) ----------------------------
    char* wsb = (char*)d_ws;
    short*    Wt   = (short*)wsb;
    size_t off = (size_t)IN_DIM * OUT_DIM * sizeof(short);          // 32 KB
    ushort_t* z_bf = (ushort_t*)(wsb + off);
    off += (size_t)n_nodes * OUT_DIM * sizeof(ushort_t);            // 6.4 MB
    float*    s_l  = (float*)(wsb + off);  off += (size_t)n_nodes * 4;
    float*    s_r  = (float*)(wsb + off);  off += (size_t)n_nodes * 4;
    int*      cnt  = (int*)(wsb + off);    off += ((size_t)nbuck * 4 + 15) & ~(size_t)15;
    unsigned* perm = (unsigned*)(wsb + off);                        // nbuck*CAP*4 = 6.4 MB

    const int ms_blocks   = (n_edges + EPB - 1) / EPB;   // 196
    const int gemm_blocks = (n_nodes + 63) / 64;         // 782

    hipMemsetAsync(cnt, 0, (size_t)nbuck * sizeof(int), stream);
    prep_kernel<<<8, 256, 0, stream>>>(W, Wt);
    fused_kernel<<<ms_blocks + gemm_blocks, 256, 0, stream>>>(
        h, Wt, a_attn, z_bf, s_l, s_r, edge_src, edge_dst, cnt, perm,
        n_nodes, n_edges, nbuck, ms_blocks);
    gather_kernel<<<nbuck, 256, 0, stream>>>(
        perm, cnt, s_l, s_r, z_bf, out, n_nodes);
}

// Round 8
// 136.995 us; speedup vs baseline: 3.1106x; 3.1106x over previous
//
#include <hip/hip_runtime.h>

#define IN_DIM   256
#define OUT_DIM  64
#define NEG_SLOPE 0.01f
#define KPAD (IN_DIM + 8)     // bf16; +16B pad -> conflict-light ds accesses
#define MAXBUCK 2048
#define CAP     1024          // slots/bucket (mean 512, 22 sigma < 1024)
#define EPB     4096          // edges per multisplit block

typedef __attribute__((ext_vector_type(8))) short short8;   // 8 bf16
typedef __attribute__((ext_vector_type(4))) float f32x4;
typedef unsigned short ushort_t;

__device__ inline unsigned f2bf_u(float f) {
    unsigned u = __float_as_uint(f);
    return (u + 0x7FFF + ((u >> 16) & 1)) >> 16;            // RNE, low 16 bits
}
__device__ inline short f2bf(float f) { return (short)f2bf_u(f); }
__device__ inline float bf2f(unsigned u16) { return __uint_as_float(u16 << 16); }

// ---------------------------------------------------------------------------
// P0 (8 blocks): W (256x64 fp32 [k][n]) -> Wt (64x256 bf16 [n][k]).
// cnt zeroing is a hipMemsetAsync on the stream.
// ---------------------------------------------------------------------------
__global__ __launch_bounds__(256)
void prep_kernel(const float* __restrict__ W, short* __restrict__ Wt)
{
    const int g = blockIdx.x * 256 + threadIdx.x;
    for (int i = g; i < IN_DIM * OUT_DIM; i += 8 * 256) {
        const int k = i & (IN_DIM - 1);
        const int n = i >> 8;                      // IN_DIM == 256
        Wt[i] = f2bf(W[(size_t)k * OUT_DIM + n]);
    }
}

// ---------------------------------------------------------------------------
// K1 (fused): blocks [0, ms_blocks) do the bucketed multisplit; the rest do
// the MFMA gemm (z = h@W + fused s_l/s_r). Data-independent halves overlap.
// ---------------------------------------------------------------------------
__global__ __launch_bounds__(256, 4)
void fused_kernel(const float* __restrict__ h, const short* __restrict__ Wt,
                  const float* __restrict__ a_attn,
                  ushort_t* __restrict__ z_bf, float* __restrict__ s_l,
                  float* __restrict__ s_r,
                  const int* __restrict__ esrc, const int* __restrict__ edst,
                  int* __restrict__ cnt, unsigned* __restrict__ perm,
                  int n_nodes, int n_edges, int nbuck, int ms_blocks)
{
    __shared__ union {
        short As[64 * KPAD];                                // 33792 B (gemm)
        struct { int hist[MAXBUCK]; int cur[MAXBUCK]; } m;  // 16384 B (multisplit)
    } sm;

    const int tid = threadIdx.x;

    if ((int)blockIdx.x < ms_blocks) {
        // ---------------- multisplit ----------------
        for (int i = tid; i < nbuck; i += 256) sm.m.hist[i] = 0;
        __syncthreads();
        const int base = blockIdx.x * EPB;
        unsigned pw[EPB / 256];
#pragma unroll
        for (int j = 0; j < EPB / 256; ++j) {
            const int i = base + j * 256 + tid;
            unsigned w = 0xFFFFFFFFu;
            if (i < n_edges) {
                const int d = edst[i];
                w = ((unsigned)d << 16) | (unsigned)esrc[i];
                atomicAdd(&sm.m.hist[d >> 5], 1);
            }
            pw[j] = w;
        }
        __syncthreads();
        for (int i = tid; i < nbuck; i += 256) {
            const int hv = sm.m.hist[i];
            if (hv) sm.m.cur[i] = i * CAP + atomicAdd(&cnt[i], hv);
        }
        __syncthreads();
#pragma unroll
        for (int j = 0; j < EPB / 256; ++j) {
            const unsigned w = pw[j];
            if (w != 0xFFFFFFFFu) {
                const int bk = (int)(w >> 21);
                const int pos = atomicAdd(&sm.m.cur[bk], 1);
                if (pos < (bk + 1) * CAP) perm[pos] = w;   // overflow guard
            }
        }
        return;
    }

    // ---------------- gemm: z = h @ W, fused s_l/s_r ----------------
    const int wave = tid >> 6;
    const int lane = tid & 63;
    const int nbase = ((int)blockIdx.x - ms_blocks) * 64;

    // stage A: one float4 load -> packed uint2 -> single ds_write_b64
    for (int i = tid; i < 64 * (IN_DIM / 4); i += 256) {
        const int m  = i >> 6;
        const int k4 = i & 63;
        int node = nbase + m;
        if (node >= n_nodes) node = n_nodes - 1;
        const float4 h4 = *(const float4*)&h[(size_t)node * IN_DIM + k4 * 4];
        uint2 p;
        p.x = f2bf_u(h4.x) | (f2bf_u(h4.y) << 16);
        p.y = f2bf_u(h4.z) | (f2bf_u(h4.w) << 16);
        *(uint2*)&sm.As[m * KPAD + k4 * 4] = p;
    }
    __syncthreads();

    f32x4 acc[4];
#pragma unroll
    for (int t = 0; t < 4; ++t) acc[t] = (f32x4){0.f, 0.f, 0.f, 0.f};

    const int col0 = lane & 15;
    const int quad = lane >> 4;
    const int mrow = wave * 16 + col0;
    const int kq   = quad * 8;

#pragma unroll
    for (int ks = 0; ks < IN_DIM / 32; ++ks) {
        const int kb = ks * 32 + kq;
        const short8 a = *(const short8*)&sm.As[mrow * KPAD + kb];
#pragma unroll
        for (int t = 0; t < 4; ++t) {
            const short8 b = *(const short8*)&Wt[(t * 16 + col0) * IN_DIM + kb];
            acc[t] = __builtin_amdgcn_mfma_f32_16x16x32_bf16(a, b, acc[t], 0, 0, 0);
        }
    }

    float al[4], ar[4];
#pragma unroll
    for (int t = 0; t < 4; ++t) {
        al[t] = a_attn[t * 16 + col0];
        ar[t] = a_attn[OUT_DIM + t * 16 + col0];
    }
#pragma unroll
    for (int r = 0; r < 4; ++r) {
        const int m = nbase + wave * 16 + quad * 4 + r;
        const bool live = m < n_nodes;
        float sl = 0.f, sr = 0.f;
#pragma unroll
        for (int t = 0; t < 4; ++t) {
            const float v = acc[t][r];
            if (live) z_bf[(size_t)m * OUT_DIM + t * 16 + col0] = (ushort_t)f2bf(v);
            sl += v * al[t];
            sr += v * ar[t];
        }
#pragma unroll
        for (int off = 1; off < 16; off <<= 1) {
            sl += __shfl_xor(sl, off, 16);
            sr += __shfl_xor(sr, off, 16);
        }
        if (live && col0 == 0) { s_l[m] = sl; s_r[m] = sr; }
    }
}

// ---------------------------------------------------------------------------
// K2: fused per-bucket CSR + softmax gather (R6 design: CSR built in LDS,
// register accumulation, x8-unrolled independent gathers for MLP).
// One block (512 thr) per bucket; quarter-wave (16 lanes) per dst.
// ---------------------------------------------------------------------------
__global__ __launch_bounds__(512)
void gather_kernel(const unsigned* __restrict__ perm, const int* __restrict__ cnt,
                   const float* __restrict__ s_l, const float* __restrict__ s_r,
                   const ushort_t* __restrict__ z_bf, float* __restrict__ out,
                   int n_nodes)
{
    __shared__ unsigned eds[CAP];
    __shared__ ushort_t srcs[CAP];
    __shared__ int hist[32], starts[33], cur[32];

    const int tid = threadIdx.x;
    const int b   = blockIdx.x;
    int nE = cnt[b];
    if (nE > CAP) nE = CAP;

    if (tid < 32) hist[tid] = 0;
    __syncthreads();

    for (int i = tid; i < nE; i += 512) {
        const unsigned p = perm[(size_t)b * CAP + i];
        eds[i] = p;
        atomicAdd(&hist[(p >> 16) & 31], 1);
    }
    __syncthreads();

    if (tid < 32) {
        const int v = hist[tid];
        int inc = v;
#pragma unroll
        for (int off = 1; off < 32; off <<= 1) {
            const int u = __shfl_up(inc, off, 32);
            if (tid >= off) inc += u;
        }
        starts[tid + 1] = inc;
        cur[tid] = inc - v;
        if (tid == 0) starts[0] = 0;
    }
    __syncthreads();

    for (int i = tid; i < nE; i += 512) {
        const unsigned p = eds[i];
        const int pos = atomicAdd(&cur[(p >> 16) & 31], 1);
        srcs[pos] = (ushort_t)(p & 0xFFFFu);
    }
    __syncthreads();

    const int ld = tid >> 4;        // 0..31: dst within bucket
    const int c  = tid & 15;        // column quad
    const int d  = b * 32 + ld;
    if (d >= n_nodes) return;

    int k = starts[ld];
    const int ke = starts[ld + 1];
    const float srd = s_r[d];

    float a0 = 0.f, a1 = 0.f, a2 = 0.f, a3 = 0.f, den = 0.f;

    for (; k + 8 <= ke; k += 8) {
        int   s[8];
        float l[8];
        uint2 q[8];
#pragma unroll
        for (int j = 0; j < 8; ++j) s[j] = srcs[k + j];
#pragma unroll
        for (int j = 0; j < 8; ++j) {
            l[j] = s_l[s[j]];
            q[j] = *(const uint2*)&z_bf[(size_t)s[j] * OUT_DIM + c * 4];
        }
#pragma unroll
        for (int j = 0; j < 8; ++j) {
            float e = l[j] + srd;
            e = e > 0.f ? e : NEG_SLOPE * e;
            const float x = __expf(e);
            den += x;
            a0 += x * bf2f(q[j].x & 0xFFFFu);
            a1 += x * bf2f(q[j].x >> 16);
            a2 += x * bf2f(q[j].y & 0xFFFFu);
            a3 += x * bf2f(q[j].y >> 16);
        }
    }
    for (; k + 4 <= ke; k += 4) {
        int   s[4];
        float l[4];
        uint2 q[4];
#pragma unroll
        for (int j = 0; j < 4; ++j) s[j] = srcs[k + j];
#pragma unroll
        for (int j = 0; j < 4; ++j) {
            l[j] = s_l[s[j]];
            q[j] = *(const uint2*)&z_bf[(size_t)s[j] * OUT_DIM + c * 4];
        }
#pragma unroll
        for (int j = 0; j < 4; ++j) {
            float e = l[j] + srd;
            e = e > 0.f ? e : NEG_SLOPE * e;
            const float x = __expf(e);
            den += x;
            a0 += x * bf2f(q[j].x & 0xFFFFu);
            a1 += x * bf2f(q[j].x >> 16);
            a2 += x * bf2f(q[j].y & 0xFFFFu);
            a3 += x * bf2f(q[j].y >> 16);
        }
    }
    for (; k < ke; ++k) {
        const int s0 = srcs[k];
        float e = s_l[s0] + srd;
        e = e > 0.f ? e : NEG_SLOPE * e;
        const float x = __expf(e);
        const uint2 q0 = *(const uint2*)&z_bf[(size_t)s0 * OUT_DIM + c * 4];
        den += x;
        a0 += x * bf2f(q0.x & 0xFFFFu);
        a1 += x * bf2f(q0.x >> 16);
        a2 += x * bf2f(q0.y & 0xFFFFu);
        a3 += x * bf2f(q0.y >> 16);
    }

    const float inv = den > 0.f ? 1.f / den : 0.f;
    float4 o;
    o.x = a0 * inv; o.y = a1 * inv; o.z = a2 * inv; o.w = a3 * inv;
    *(float4*)&out[(size_t)d * OUT_DIM + c * 4] = o;
}

extern "C" void kernel_launch(void* const* d_in, const int* in_sizes, int n_in,
                              void* d_out, int out_size, void* d_ws, size_t ws_size,
                              hipStream_t stream)
{
    const float* h        = (const float*)d_in[0];
    const int*   edge_src = (const int*)  d_in[1];
    const int*   edge_dst = (const int*)  d_in[2];
    const float* W        = (const float*)d_in[3];
    const float* a_attn   = (const float*)d_in[4];
    float*       out      = (float*)d_out;

    const int n_nodes = in_sizes[0] / IN_DIM;   // 50000
    const int n_edges = in_sizes[1];            // 800000
    const int nbuck   = (n_nodes + 31) >> 5;    // 1563

    // ---- workspace layout (16B-aligned regions) ----------------------------
    char* wsb = (char*)d_ws;
    short*    Wt   = (short*)wsb;
    size_t off = (size_t)IN_DIM * OUT_DIM * sizeof(short);          // 32 KB
    ushort_t* z_bf = (ushort_t*)(wsb + off);
    off += (size_t)n_nodes * OUT_DIM * sizeof(ushort_t);            // 6.4 MB
    float*    s_l  = (float*)(wsb + off);  off += (size_t)n_nodes * 4;
    float*    s_r  = (float*)(wsb + off);  off += (size_t)n_nodes * 4;
    int*      cnt  = (int*)(wsb + off);    off += ((size_t)nbuck * 4 + 15) & ~(size_t)15;
    unsigned* perm = (unsigned*)(wsb + off);                        // nbuck*CAP*4 = 6.4 MB

    const int ms_blocks   = (n_edges + EPB - 1) / EPB;   // 196
    const int gemm_blocks = (n_nodes + 63) / 64;         // 782

    hipMemsetAsync(cnt, 0, (size_t)nbuck * sizeof(int), stream);
    prep_kernel<<<8, 256, 0, stream>>>(W, Wt);
    fused_kernel<<<ms_blocks + gemm_blocks, 256, 0, stream>>>(
        h, Wt, a_attn, z_bf, s_l, s_r, edge_src, edge_dst, cnt, perm,
        n_nodes, n_edges, nbuck, ms_blocks);
    gather_kernel<<<nbuck, 512, 0, stream>>>(
        perm, cnt, s_l, s_r, z_bf, out, n_nodes);
}